// Round 1
// 131.350 us; speedup vs baseline: 1.0503x; 1.0503x over previous
//
#include <hip/hip_runtime.h>
#include <hip/hip_bf16.h>

typedef unsigned char u8;
typedef unsigned short u16;
typedef unsigned int u32;
typedef float f32x16 __attribute__((ext_vector_type(16)));
typedef float f32x2 __attribute__((ext_vector_type(2)));
typedef int i32x4 __attribute__((ext_vector_type(4)));
typedef int i32x8 __attribute__((ext_vector_type(8)));

#define B_SZ 8192
#define D_SZ 768
#define TAU_INV 10.0f
// elements scaled by 32 -> logits scaled by 1024; exp2 const = log2(e)*10/1024
#define ESCALE 0.014088818758681283f
#define FP4_SCALE 32.0f
// Schraudolph fast-exp2: e = as_float((int)(x*K1 + K2)), K1 = ESCALE*2^23,
// K2 = 127*2^23 - sigma, sigma = 0.05645*2^23 (mean-zero error for sums)
#define SCHRAU_K1 118185.58f
#define SCHRAU_K2 1064879685.0f

// FP4 tiled operand layout: tile = 32 rows x 64 k-elems x 0.5 B = 1024 B,
// tiles indexed (rowgroup rg = row>>5) * 12 + (kblock kb = k>>6).
// Within a tile, byte for (row r, k) at  h*512 + (r&31)*16 + ((k&31)>>1),
// nibble = k&1 (low nibble = even k), where h=(k>>5)&1.
// Consequence: an MFMA fragment read is ONE coalesced dwordx4 at base+lane*16.

// fp32 -> e2m1 nibble, round-to-nearest (values 0,.5,1,1.5,2,3,4,6; clamp at 6)
__device__ __forceinline__ u32 fp4_enc(float x) {
    float y = fabsf(x);
    u32 n = (u32)(y >= 0.25f) + (u32)(y >= 0.75f) + (u32)(y >= 1.25f) +
            (u32)(y >= 1.75f) + (u32)(y >= 2.5f)  + (u32)(y >= 3.5f) +
            (u32)(y >= 5.0f);
    return n | (x < 0.f ? 8u : 0u);
}

__device__ __forceinline__ u16 fp4_pack4(float x, float y, float z, float w) {
    return (u16)(fp4_enc(x) | (fp4_enc(y) << 4) | (fp4_enc(z) << 8) | (fp4_enc(w) << 12));
}

// ---------------- Kernel 1: row norms, fp4 normalize (x32), tiled store, fp32 diag ----------
__global__ __launch_bounds__(256) void norm_kernel(const float4* __restrict__ v,
                                                   const float4* __restrict__ u,
                                                   u16* __restrict__ vn,
                                                   u16* __restrict__ un,
                                                   float* __restrict__ diag) {
    const int wid = threadIdx.x >> 6, lane = threadIdx.x & 63;
    const int row = blockIdx.x * 4 + wid;
    const float4* vr = v + (size_t)row * 192;
    const float4* ur = u + (size_t)row * 192;
    float4 a[3], b[3];
    float sv = 0.f, su = 0.f, sd = 0.f;
#pragma unroll
    for (int c = 0; c < 3; ++c) {
        a[c] = vr[lane + 64 * c];
        b[c] = ur[lane + 64 * c];
        sv += a[c].x * a[c].x + a[c].y * a[c].y + a[c].z * a[c].z + a[c].w * a[c].w;
        su += b[c].x * b[c].x + b[c].y * b[c].y + b[c].z * b[c].z + b[c].w * b[c].w;
        sd += a[c].x * b[c].x + a[c].y * b[c].y + a[c].z * b[c].z + a[c].w * b[c].w;
    }
#pragma unroll
    for (int m = 1; m < 64; m <<= 1) {
        sv += __shfl_xor(sv, m);
        su += __shfl_xor(su, m);
        sd += __shfl_xor(sd, m);
    }
    const float iv = FP4_SCALE / fmaxf(sqrtf(sv), 1e-8f);
    const float iu = FP4_SCALE / fmaxf(sqrtf(su), 1e-8f);
    const int rg = row >> 5, rr = row & 31;
#pragma unroll
    for (int c = 0; c < 3; ++c) {
        u16 pa = fp4_pack4(a[c].x * iv, a[c].y * iv, a[c].z * iv, a[c].w * iv);
        u16 pb = fp4_pack4(b[c].x * iu, b[c].y * iu, b[c].z * iu, b[c].w * iu);
        const int e = lane + 64 * c;   // float4 index within the row (k = 4e..4e+3)
        // u16 index: tile*(1024/2) + h*256 + rr*8 + (e&7)
        const int idx = (rg * 12 + (e >> 4)) * 512 + ((e >> 3) & 1) * 256 + rr * 8 + (e & 7);
        vn[idx] = pa;
        un[idx] = pb;
    }
    if (lane == 0) diag[row] = sd * iv * iu * TAU_INV / (FP4_SCALE * FP4_SCALE);
}

// saddr-form fp4 fragment load: ONE dwordx4 at wave-uniform base + per-lane off.
// fp4 MFMA (cbsz=4/blgp=4) reads only v[0:3] of the 8-reg operand; upper half
// is left UNDEF (no duplication movs, regalloc freedom).
__device__ __forceinline__ i32x8 ldfrag4(const u8* __restrict__ base, u32 off) {
    i32x4 lo = *(const i32x4*)(base + off);
    return __builtin_shufflevector(lo, lo, 0, 1, 2, 3, -1, -1, -1, -1);
}

__device__ __forceinline__ f32x16 mx_mfma4(i32x8 a, i32x8 b, f32x16 c) {
    // cbsz=4 (A fmt E2M1), blgp=4 (B fmt E2M1), scales = 127 -> 1.0
    return __builtin_amdgcn_mfma_scale_f32_32x32x64_f8f6f4(
        a, b, c, 4, 4, 0, 0x7F7F7F7F, 0, 0x7F7F7F7F);
}

// ------- Kernel 2: 128x128 fp4 MX MFMA tile (BK=64). NO LDS staging, NO K-loop barriers;
//         saddr loads (1 dwordx4/fragment), 2-slot register pipeline, 4 waves/SIMD;
//         setprio around MFMA clusters; packed-f32 Schraudolph epilogue with
//         fold-reduce (transpose-reduce) instead of butterfly allreduce -------
__global__ __launch_bounds__(256, 4) void simexp_kernel(const u8* __restrict__ vn,
                                                        const u8* __restrict__ un,
                                                        float* __restrict__ rowP,
                                                        float* __restrict__ colP) {
    __shared__ float rowLds[2][128];
    __shared__ float colLds[2][128];

    const int tid  = threadIdx.x;
    const int wid  = tid >> 6;
    const int lane = tid & 63;
    const int l32  = lane & 31;
    const int h    = lane >> 5;
    const int wr = wid >> 1, wc = wid & 1;

    // 8x8 chunked grid for L2 locality
    const int id = blockIdx.x;
    const int chunk = id >> 6;
    const int li = id & 63;
    const int rb = ((chunk >> 3) << 3) + (li >> 3);
    const int cb = ((chunk & 7) << 3) + (li & 7);

    // wave-uniform SGPR base pointers (row-group stride = 12 tiles = 12288 B)
    const int aBase = __builtin_amdgcn_readfirstlane((rb * 4 + wr * 2) * 12288);
    const int bBase = __builtin_amdgcn_readfirstlane((cb * 4 + wc * 2) * 12288);
    const u8* __restrict__ A0 = vn + aBase;
    const u8* __restrict__ A1 = A0 + 12288;
    const u8* __restrict__ B0 = un + bBase;
    const u8* __restrict__ B1 = B0 + 12288;
    u32 voff = (u32)lane * 16;   // per-lane offset; +1024 after each slot-load

    f32x16 acc[2][2];
#pragma unroll
    for (int i = 0; i < 2; ++i)
#pragma unroll
        for (int j = 0; j < 2; ++j)
#pragma unroll
            for (int r = 0; r < 16; ++r) acc[i][j][r] = 0.f;

    i32x8 fa[2][2], fb[2][2];

#define LOAD_SLOT(s)                        \
    {                                       \
        fa[s][0] = ldfrag4(A0, voff);       \
        fa[s][1] = ldfrag4(A1, voff);       \
        fb[s][0] = ldfrag4(B0, voff);       \
        fb[s][1] = ldfrag4(B1, voff);       \
        voff += 1024;                       \
    }
#define MFMA_SLOT(s)                                          \
    {                                                         \
        __builtin_amdgcn_s_setprio(1);                        \
        acc[0][0] = mx_mfma4(fa[s][0], fb[s][0], acc[0][0]);  \
        acc[1][0] = mx_mfma4(fa[s][1], fb[s][0], acc[1][0]);  \
        acc[0][1] = mx_mfma4(fa[s][0], fb[s][1], acc[0][1]);  \
        acc[1][1] = mx_mfma4(fa[s][1], fb[s][1], acc[1][1]);  \
        __builtin_amdgcn_s_setprio(0);                        \
    }

    LOAD_SLOT(0)                     // tile 0
#pragma unroll 1
    for (int it = 0; it < 12; it += 2) {
        LOAD_SLOT(1)                 // tile it+1 — issued before consuming tile it
        MFMA_SLOT(0)
        if (it + 2 < 12) LOAD_SLOT(0)
        MFMA_SLOT(1)
    }

    // ---------------- Epilogue v2 ----------------
    // 32x32 C/D layout: col = lane&31, row = (reg&3) + 8*(reg>>2) + 4*h.
    // exp via Schraudolph on PACKED f32 pairs (v_pk_fma_f32 / v_pk_add_f32):
    // 5 instrs per 2 elements instead of 8 scalar.
    f32x2 val2[16];            // [i*8 + r/2] row-sum partials (pairs of regs)
    f32x2 cacc2[2];            // [j] col-sum partials (pair halves summed later)
#pragma unroll
    for (int p = 0; p < 16; ++p) { val2[p].x = 0.f; val2[p].y = 0.f; }
    cacc2[0].x = 0.f; cacc2[0].y = 0.f;
    cacc2[1].x = 0.f; cacc2[1].y = 0.f;
#pragma unroll
    for (int i = 0; i < 2; ++i)
#pragma unroll
        for (int j = 0; j < 2; ++j)
#pragma unroll
            for (int r = 0; r < 16; r += 2) {
                f32x2 a;
                a.x = acc[i][j][r];
                a.y = acc[i][j][r + 1];
                f32x2 t = a * SCHRAU_K1 + SCHRAU_K2;   // contracts to v_pk_fma_f32
                f32x2 e;
                e.x = __int_as_float((int)t.x);
                e.y = __int_as_float((int)t.y);
                val2[i * 8 + (r >> 1)] += e;
                cacc2[j] += e;
            }

    // Fold-reduce (transpose-reduce) over the 32 columns (lanes of same h):
    // merge register pairs while reducing lanes; 15 merges + 1 lane-pair
    // collapse ≈ 34 ds_swizzle total (vs 160 for butterfly allreduce), and each
    // lane ends OWNING one row's total -> single LDS store, no exec-mask loop.
#pragma unroll
    for (int m = 16; m >= 2; m >>= 1) {
        const int n = m >> 1;
        const bool hi = (l32 & m) != 0;
#pragma unroll
        for (int p = 0; p < n; ++p) {
            f32x2 a = val2[p], b = val2[p + n];
            f32x2 x, y;
            x.x = hi ? b.x : a.x;  x.y = hi ? b.y : a.y;
            y.x = hi ? a.x : b.x;  y.y = hi ? a.y : b.y;
            f32x2 s;
            s.x = __shfl_xor(y.x, m);
            s.y = __shfl_xor(y.y, m);
            val2[p] = x + s;
        }
    }
    {   // lanes l and l^1 hold complementary 16-lane partials of the same pair
        f32x2 s;
        s.x = __shfl_xor(val2[0].x, 1);
        s.y = __shfl_xor(val2[0].y, 1);
        val2[0] += s;
    }
    // lane l32 now holds totals for value pair q = (l32>>1)&15, i.e. reg
    // indices t = 2q (.x) and 2q+1 (.y); even lane writes t=2q, odd t=2q+1.
    {
        const int q = (l32 >> 1) & 15;
        const int t = 2 * q + (l32 & 1);
        const int i = t >> 4, r = t & 15;
        const int row = wr * 64 + i * 32 + (r & 3) + 8 * (r >> 2) + 4 * h;
        rowLds[wc][row] = (l32 & 1) ? val2[0].y : val2[0].x;
    }
    // col sums: collapse the pair halves, then add the other h half (rows)
    {
        float c0 = cacc2[0].x + cacc2[0].y;
        float c1 = cacc2[1].x + cacc2[1].y;
        c0 += __shfl_xor(c0, 32);
        c1 += __shfl_xor(c1, 32);
        if (h == 0) {
            colLds[wr][wc * 64 + l32]      = c0;
            colLds[wr][wc * 64 + 32 + l32] = c1;
        }
    }
    __syncthreads();
    if (tid < 128) {
        rowP[(size_t)cb * B_SZ + rb * 128 + tid] = rowLds[0][tid] + rowLds[1][tid];
    } else {
        const int t = tid - 128;
        colP[(size_t)rb * B_SZ + cb * 128 + t] = colLds[0][t] + colLds[1][t];
    }
}

// ---------------- Kernel 3: reduce partials, log, subtract diag, mean ----------------
__global__ __launch_bounds__(256) void finalize_kernel(const float* __restrict__ rowP,
                                                       const float* __restrict__ colP,
                                                       const float* __restrict__ diag,
                                                       float* __restrict__ out) {
    const int i = blockIdx.x * 256 + threadIdx.x;
    float rs = 0.f, cs = 0.f;
#pragma unroll 8
    for (int p = 0; p < 64; ++p) {
        rs += rowP[(size_t)p * B_SZ + i];
        cs += colP[(size_t)p * B_SZ + i];
    }
    float contrib = (0.75f * logf(rs) + 0.25f * logf(cs) - diag[i]) * (1.0f / (float)B_SZ);
#pragma unroll
    for (int m = 1; m < 64; m <<= 1) contrib += __shfl_xor(contrib, m);
    __shared__ float red[4];
    const int wid = threadIdx.x >> 6, lane = threadIdx.x & 63;
    if (lane == 0) red[wid] = contrib;
    __syncthreads();
    if (threadIdx.x == 0) atomicAdd(out, red[0] + red[1] + red[2] + red[3]);
}

extern "C" void kernel_launch(void* const* d_in, const int* in_sizes, int n_in,
                              void* d_out, int out_size, void* d_ws, size_t ws_size,
                              hipStream_t stream) {
    const float* v = (const float*)d_in[0];
    const float* u = (const float*)d_in[1];
    char* ws = (char*)d_ws;
    // workspace layout (~10.5 MB)
    u16* vn4   = (u16*)(ws);                    // 8192*384 B  = 3,145,728
    u16* un4   = (u16*)(ws + 3145728);          // 3,145,728
    float* dg  = (float*)(ws + 6291456);        // 8192*4      = 32,768
    float* rwp = (float*)(ws + 6324224);        // 64*8192*4   = 2,097,152
    float* clp = (float*)(ws + 8421376);        // 2,097,152
    float* out = (float*)d_out;

    hipMemsetAsync(out, 0, sizeof(float), stream);
    hipLaunchKernelGGL(norm_kernel, dim3(2048), dim3(256), 0, stream,
                       (const float4*)v, (const float4*)u, vn4, un4, dg);
    hipLaunchKernelGGL(simexp_kernel, dim3(4096), dim3(256), 0, stream,
                       (const u8*)vn4, (const u8*)un4, rwp, clp);
    hipLaunchKernelGGL(finalize_kernel, dim3(B_SZ / 256), dim3(256), 0, stream, rwp, clp, dg, out);
}

// Round 2
// 125.488 us; speedup vs baseline: 1.0994x; 1.0467x over previous
//
#include <hip/hip_runtime.h>
#include <hip/hip_bf16.h>

typedef unsigned char u8;
typedef unsigned short u16;
typedef unsigned int u32;
typedef float f32x16 __attribute__((ext_vector_type(16)));
typedef float f32x2 __attribute__((ext_vector_type(2)));
typedef int i32x4 __attribute__((ext_vector_type(4)));
typedef int i32x8 __attribute__((ext_vector_type(8)));

#define B_SZ 8192
#define D_SZ 768
#define TAU_INV 10.0f
// elements scaled by 32 -> logits scaled by 1024; exp2 const = log2(e)*10/1024
#define ESCALE 0.014088818758681283f
#define FP4_SCALE 32.0f
// Schraudolph fast-exp2: e = as_float((int)(x*K1 + K2)), K1 = ESCALE*2^23,
// K2 = 127*2^23 - sigma, sigma = 0.05645*2^23 (mean-zero error for sums)
#define SCHRAU_K1 118185.58f
#define SCHRAU_K2 1064879685.0f

// FP4 tiled operand layout: tile = 32 rows x 64 k-elems x 0.5 B = 1024 B,
// tiles indexed (rowgroup rg = row>>5) * 12 + (kblock kb = k>>6).
// Within a tile, byte for (row r, k) at  h*512 + (r&31)*16 + ((k&31)>>1),
// nibble = k&1 (low nibble = even k), where h=(k>>5)&1.
// Consequence: an MFMA fragment read is ONE coalesced dwordx4 at base+lane*16,
// and a tile stages into LDS with ONE global_load_lds (64 lanes x 16 B, linear).

// fp32 -> e2m1 nibble, round-to-nearest (values 0,.5,1,1.5,2,3,4,6; clamp at 6)
__device__ __forceinline__ u32 fp4_enc(float x) {
    float y = fabsf(x);
    u32 n = (u32)(y >= 0.25f) + (u32)(y >= 0.75f) + (u32)(y >= 1.25f) +
            (u32)(y >= 1.75f) + (u32)(y >= 2.5f)  + (u32)(y >= 3.5f) +
            (u32)(y >= 5.0f);
    return n | (x < 0.f ? 8u : 0u);
}

__device__ __forceinline__ u16 fp4_pack4(float x, float y, float z, float w) {
    return (u16)(fp4_enc(x) | (fp4_enc(y) << 4) | (fp4_enc(z) << 8) | (fp4_enc(w) << 12));
}

// ---------------- Kernel 1: row norms, fp4 normalize (x32), tiled store, fp32 diag ----------
__global__ __launch_bounds__(256) void norm_kernel(const float4* __restrict__ v,
                                                   const float4* __restrict__ u,
                                                   u16* __restrict__ vn,
                                                   u16* __restrict__ un,
                                                   float* __restrict__ diag) {
    const int wid = threadIdx.x >> 6, lane = threadIdx.x & 63;
    const int row = blockIdx.x * 4 + wid;
    const float4* vr = v + (size_t)row * 192;
    const float4* ur = u + (size_t)row * 192;
    float4 a[3], b[3];
    float sv = 0.f, su = 0.f, sd = 0.f;
#pragma unroll
    for (int c = 0; c < 3; ++c) {
        a[c] = vr[lane + 64 * c];
        b[c] = ur[lane + 64 * c];
        sv += a[c].x * a[c].x + a[c].y * a[c].y + a[c].z * a[c].z + a[c].w * a[c].w;
        su += b[c].x * b[c].x + b[c].y * b[c].y + b[c].z * b[c].z + b[c].w * b[c].w;
        sd += a[c].x * b[c].x + a[c].y * b[c].y + a[c].z * b[c].z + a[c].w * b[c].w;
    }
#pragma unroll
    for (int m = 1; m < 64; m <<= 1) {
        sv += __shfl_xor(sv, m);
        su += __shfl_xor(su, m);
        sd += __shfl_xor(sd, m);
    }
    const float iv = FP4_SCALE / fmaxf(sqrtf(sv), 1e-8f);
    const float iu = FP4_SCALE / fmaxf(sqrtf(su), 1e-8f);
    const int rg = row >> 5, rr = row & 31;
#pragma unroll
    for (int c = 0; c < 3; ++c) {
        u16 pa = fp4_pack4(a[c].x * iv, a[c].y * iv, a[c].z * iv, a[c].w * iv);
        u16 pb = fp4_pack4(b[c].x * iu, b[c].y * iu, b[c].z * iu, b[c].w * iu);
        const int e = lane + 64 * c;   // float4 index within the row (k = 4e..4e+3)
        // u16 index: tile*(1024/2) + h*256 + rr*8 + (e&7)
        const int idx = (rg * 12 + (e >> 4)) * 512 + ((e >> 3) & 1) * 256 + rr * 8 + (e & 7);
        vn[idx] = pa;
        un[idx] = pb;
    }
    if (lane == 0) diag[row] = sd * iv * iu * TAU_INV / (FP4_SCALE * FP4_SCALE);
}

// LDS fragment read: ONE ds_read_b128; fp4 MFMA (cbsz=4/blgp=4) reads only
// v[0:3] of the 8-reg operand; upper half left UNDEF.
__device__ __forceinline__ i32x8 ldsfrag(const u8* p) {
    i32x4 lo = *(const i32x4*)p;
    return __builtin_shufflevector(lo, lo, 0, 1, 2, 3, -1, -1, -1, -1);
}

__device__ __forceinline__ void gload_lds16(const u8* g, u8* l) {
    __builtin_amdgcn_global_load_lds((const __attribute__((address_space(1))) void*)g,
                                     (__attribute__((address_space(3))) void*)l, 16, 0, 0);
}

__device__ __forceinline__ f32x16 mx_mfma4(i32x8 a, i32x8 b, f32x16 c) {
    // cbsz=4 (A fmt E2M1), blgp=4 (B fmt E2M1), scales = 127 -> 1.0
    return __builtin_amdgcn_mfma_scale_f32_32x32x64_f8f6f4(
        a, b, c, 4, 4, 0, 0x7F7F7F7F, 0, 0x7F7F7F7F);
}

// ------- Kernel 2: 256x256 fp4 MX MFMA block tile, 16 waves (1024 thr) of 64x64.
//         LDS-staged operands via global_load_lds (1 KB/wave/step), 3-slot
//         prefetch-depth-2 pipeline, counted s_waitcnt vmcnt(1) + raw s_barrier
//         per K-step (never a full drain); setprio around MFMA; packed-f32
//         Schraudolph epilogue with fold-reduce -------
__global__ __launch_bounds__(1024, 4) void simexp_kernel(const u8* __restrict__ vn,
                                                         const u8* __restrict__ un,
                                                         float* __restrict__ rowP,
                                                         float* __restrict__ colP) {
    // [slot][tile: 0-7 = A rowgroups, 8-15 = B rowgroups][1024 B]
    __shared__ __attribute__((aligned(16))) u8 stg[3][16][1024];   // 48 KB
    __shared__ float rowLds[4][256];                                // 4 KB
    __shared__ float colLds[4][256];                                // 4 KB

    const int tid  = threadIdx.x;
    const int w    = tid >> 6;       // wave 0..15
    const int lane = tid & 63;
    const int l32  = lane & 31;
    const int h    = lane >> 5;
    const int wr = w >> 2, wc = w & 3;   // 4x4 wave grid, 64x64 tile each

    // 1024 blocks = 16 chunks of 64 (8rb x 8cb) for L2 locality
    const int id = blockIdx.x;
    const int chunk = id >> 6;
    const int li = id & 63;
    const int rb = ((chunk >> 2) << 3) + (li >> 3);   // 0..31
    const int cb = ((chunk & 3) << 3) + (li & 7);     // 0..31

    // staging: wave w stages tile w each K-step (one 1 KB global_load_lds).
    // tile w<8: A rowgroup rb*8+w ; w>=8: B rowgroup cb*8+(w-8). rowgroup
    // stride = 12 tiles = 12288 B; K-step stride = 1024 B.
    const u8* gsrc = (w < 8 ? vn + (size_t)(rb * 8 + w) * 12288
                            : un + (size_t)(cb * 8 + (w - 8)) * 12288)
                     + (u32)lane * 16;

    f32x16 acc[2][2];
#pragma unroll
    for (int i = 0; i < 2; ++i)
#pragma unroll
        for (int j = 0; j < 2; ++j)
#pragma unroll
            for (int r = 0; r < 16; ++r) acc[i][j][r] = 0.f;

#define STAGE(t) gload_lds16(gsrc + (t) * 1024, &stg[(t) % 3][w][0]);

    // prologue: prefetch K-steps 0 and 1
    STAGE(0)
    STAGE(1)
    asm volatile("s_waitcnt vmcnt(1)\n\ts_barrier" ::: "memory");

#pragma unroll
    for (int t = 0; t < 12; ++t) {
        if (t + 2 < 12) STAGE(t + 2)             // prefetch depth 2 into slot (t+2)%3
        const u8* base = &stg[t % 3][0][0] + (u32)lane * 16;
        i32x8 fa0 = ldsfrag(base + (wr * 2)     * 1024);
        i32x8 fa1 = ldsfrag(base + (wr * 2 + 1) * 1024);
        i32x8 fb0 = ldsfrag(base + (8 + wc * 2) * 1024);
        i32x8 fb1 = ldsfrag(base + (9 + wc * 2) * 1024);
        __builtin_amdgcn_s_setprio(1);
        acc[0][0] = mx_mfma4(fa0, fb0, acc[0][0]);
        acc[1][0] = mx_mfma4(fa1, fb0, acc[1][0]);
        acc[0][1] = mx_mfma4(fa0, fb1, acc[0][1]);
        acc[1][1] = mx_mfma4(fa1, fb1, acc[1][1]);
        __builtin_amdgcn_s_setprio(0);
        // own prefetch for step t+1 must be done (vmcnt(1): newest may fly),
        // then barrier so ALL waves' tiles for t+1 are visible. Step t=10 must
        // fully drain (its newest load, L11, is consumed next step). No sync
        // after t=11 (stg never reused; epilogue has its own __syncthreads).
        if (t < 10)       asm volatile("s_waitcnt vmcnt(1)\n\ts_barrier" ::: "memory");
        else if (t == 10) asm volatile("s_waitcnt vmcnt(0)\n\ts_barrier" ::: "memory");
    }
#undef STAGE

    // ---------------- Epilogue (per-wave identical to v2) ----------------
    // 32x32 C/D layout: col = lane&31, row = (reg&3) + 8*(reg>>2) + 4*h.
    f32x2 val2[16];            // [i*8 + r/2] row-sum partials (pairs of regs)
    f32x2 cacc2[2];            // [j] col-sum partials
#pragma unroll
    for (int p = 0; p < 16; ++p) { val2[p].x = 0.f; val2[p].y = 0.f; }
    cacc2[0].x = 0.f; cacc2[0].y = 0.f;
    cacc2[1].x = 0.f; cacc2[1].y = 0.f;
#pragma unroll
    for (int i = 0; i < 2; ++i)
#pragma unroll
        for (int j = 0; j < 2; ++j)
#pragma unroll
            for (int r = 0; r < 16; r += 2) {
                f32x2 a;
                a.x = acc[i][j][r];
                a.y = acc[i][j][r + 1];
                f32x2 t = a * SCHRAU_K1 + SCHRAU_K2;   // v_pk_fma_f32
                f32x2 e;
                e.x = __int_as_float((int)t.x);
                e.y = __int_as_float((int)t.y);
                val2[i * 8 + (r >> 1)] += e;
                cacc2[j] += e;
            }

    // Fold-reduce over the 32 columns: each lane ends owning one row total.
#pragma unroll
    for (int m = 16; m >= 2; m >>= 1) {
        const int n = m >> 1;
        const bool hi = (l32 & m) != 0;
#pragma unroll
        for (int p = 0; p < n; ++p) {
            f32x2 a = val2[p], b = val2[p + n];
            f32x2 x, y;
            x.x = hi ? b.x : a.x;  x.y = hi ? b.y : a.y;
            y.x = hi ? a.x : b.x;  y.y = hi ? a.y : b.y;
            f32x2 s;
            s.x = __shfl_xor(y.x, m);
            s.y = __shfl_xor(y.y, m);
            val2[p] = x + s;
        }
    }
    {   // lanes l and l^1 hold complementary 16-lane partials of the same pair
        f32x2 s;
        s.x = __shfl_xor(val2[0].x, 1);
        s.y = __shfl_xor(val2[0].y, 1);
        val2[0] += s;
    }
    {
        const int q = (l32 >> 1) & 15;
        const int t = 2 * q + (l32 & 1);
        const int i = t >> 4, r = t & 15;
        const int row = wr * 64 + i * 32 + (r & 3) + 8 * (r >> 2) + 4 * h;
        rowLds[wc][row] = (l32 & 1) ? val2[0].y : val2[0].x;
    }
    {
        float c0 = cacc2[0].x + cacc2[0].y;
        float c1 = cacc2[1].x + cacc2[1].y;
        c0 += __shfl_xor(c0, 32);
        c1 += __shfl_xor(c1, 32);
        if (h == 0) {
            colLds[wr][wc * 64 + l32]      = c0;
            colLds[wr][wc * 64 + 32 + l32] = c1;
        }
    }
    __syncthreads();
    if (tid < 256) {
        rowP[(size_t)cb * B_SZ + rb * 256 + tid] =
            rowLds[0][tid] + rowLds[1][tid] + rowLds[2][tid] + rowLds[3][tid];
    } else if (tid < 512) {
        const int t = tid - 256;
        colP[(size_t)rb * B_SZ + cb * 256 + t] =
            colLds[0][t] + colLds[1][t] + colLds[2][t] + colLds[3][t];
    }
}

// ---------------- Kernel 3: reduce partials, log, subtract diag, mean ----------------
__global__ __launch_bounds__(256) void finalize_kernel(const float* __restrict__ rowP,
                                                       const float* __restrict__ colP,
                                                       const float* __restrict__ diag,
                                                       float* __restrict__ out) {
    const int i = blockIdx.x * 256 + threadIdx.x;
    float rs = 0.f, cs = 0.f;
#pragma unroll 8
    for (int p = 0; p < 32; ++p) {
        rs += rowP[(size_t)p * B_SZ + i];
        cs += colP[(size_t)p * B_SZ + i];
    }
    float contrib = (0.75f * logf(rs) + 0.25f * logf(cs) - diag[i]) * (1.0f / (float)B_SZ);
#pragma unroll
    for (int m = 1; m < 64; m <<= 1) contrib += __shfl_xor(contrib, m);
    __shared__ float red[4];
    const int wid = threadIdx.x >> 6, lane = threadIdx.x & 63;
    if (lane == 0) red[wid] = contrib;
    __syncthreads();
    if (threadIdx.x == 0) atomicAdd(out, red[0] + red[1] + red[2] + red[3]);
}

extern "C" void kernel_launch(void* const* d_in, const int* in_sizes, int n_in,
                              void* d_out, int out_size, void* d_ws, size_t ws_size,
                              hipStream_t stream) {
    const float* v = (const float*)d_in[0];
    const float* u = (const float*)d_in[1];
    char* ws = (char*)d_ws;
    // workspace layout (~8.4 MB)
    u16* vn4   = (u16*)(ws);                    // 8192*384 B  = 3,145,728
    u16* un4   = (u16*)(ws + 3145728);          // 3,145,728
    float* dg  = (float*)(ws + 6291456);        // 8192*4      = 32,768
    float* rwp = (float*)(ws + 6324224);        // 32*8192*4   = 1,048,576
    float* clp = (float*)(ws + 7372800);        // 1,048,576
    float* out = (float*)d_out;

    hipMemsetAsync(out, 0, sizeof(float), stream);
    hipLaunchKernelGGL(norm_kernel, dim3(2048), dim3(256), 0, stream,
                       (const float4*)v, (const float4*)u, vn4, un4, dg);
    hipLaunchKernelGGL(simexp_kernel, dim3(1024), dim3(1024), 0, stream,
                       (const u8*)vn4, (const u8*)un4, rwp, clp);
    hipLaunchKernelGGL(finalize_kernel, dim3(B_SZ / 256), dim3(256), 0, stream, rwp, clp, dg, out);
}